// Round 5
// baseline (326.232 us; speedup 1.0000x reference)
//
#include <hip/hip_runtime.h>
#include <hip/hip_bf16.h>
#include <cstddef>

#define BB 16
#define TT 4096
#define HH 512

typedef _Float16 half8 __attribute__((ext_vector_type(8)));
typedef float f32x4 __attribute__((ext_vector_type(4)));

__device__ __forceinline__ float fast_rcp(float x) { return __builtin_amdgcn_rcpf(x); }

#define ASM_LGKM0() { asm volatile("s_waitcnt lgkmcnt(0)" ::: "memory"); __builtin_amdgcn_sched_barrier(0); }
#define PIN8(a,b,c,d,e,f,g,h) asm volatile("" : "+v"(a), "+v"(b), "+v"(c), "+v"(d), "+v"(e), "+v"(f), "+v"(g), "+v"(h))

// ---------------- prep (unchanged) ---------------------------------------------
// blocks 0..127 : pack Wv (f32 [n][k]) -> Bpack f16, layout [kb(16)][tn(32)][lane(64)][8]
// blocks 128..191: qb[b][o] = query[b]·Wq[o] + bias[o] + conv_b[o]
// block  192     : zero ssum/ctx
__global__ void prep_kernel(const float* __restrict__ query,
                            const float* __restrict__ conv_b,
                            const float* __restrict__ Wq,
                            const float* __restrict__ Wv,
                            const float* __restrict__ bias,
                            _Float16* __restrict__ Bpack,
                            float* __restrict__ qb,
                            float* __restrict__ ssum,
                            float* __restrict__ ctx) {
    int blk = blockIdx.x;
    int tid = threadIdx.x;
    if (blk < 128) {
        int tn = blk >> 2, kq = blk & 3;
        int kb = kq * 4 + (tid >> 6);
        int lane = tid & 63;
        int n = tn * 16 + (lane & 15);
        int k = kb * 32 + ((lane >> 4) << 3);
        const float4* src = (const float4*)(Wv + (size_t)n * HH + k);
        float4 v0 = src[0], v1 = src[1];
        half8 h = { (_Float16)v0.x, (_Float16)v0.y, (_Float16)v0.z, (_Float16)v0.w,
                    (_Float16)v1.x, (_Float16)v1.y, (_Float16)v1.z, (_Float16)v1.w };
        *(half8*)(Bpack + ((size_t)(kb * 32 + tn) * 64 + lane) * 8) = h;
    } else if (blk < 192) {
        int q = blk - 128;
        int b = q >> 2, oq = q & 3;
        __shared__ float qrow[HH];
        for (int i = tid; i < HH; i += 256) qrow[i] = query[b * HH + i];
        __syncthreads();
        int wave = tid >> 6, lane = tid & 63;
        float4 q1 = *(const float4*)(qrow + lane * 8);
        float4 q2 = *(const float4*)(qrow + lane * 8 + 4);
        for (int i = wave; i < 128; i += 4) {
            int o = oq * 128 + i;
            const float4* w = (const float4*)(Wq + (size_t)o * HH);
            float4 a = w[lane * 2], c = w[lane * 2 + 1];
            float acc = a.x * q1.x + a.y * q1.y + a.z * q1.z + a.w * q1.w
                      + c.x * q2.x + c.y * q2.y + c.z * q2.z + c.w * q2.w;
            #pragma unroll
            for (int off = 1; off < 64; off <<= 1) acc += __shfl_xor(acc, off, 64);
            if (lane == 0) qb[b * HH + o] = acc + bias[o] + conv_b[o];
        }
    } else {
        for (int i = tid; i < BB; i += 256) ssum[i] = 0.f;
        for (int i = tid; i < BB * HH; i += 256) ctx[i] = 0.f;
    }
}

// ---------------- fused GEMM + conv + tanh + score + sigmoid + context ---------
// Persistent pipelined design (R4 fixed):
//   grid 256 = 1 block/CU, 512 thr = 8 waves; b = blk>>4; 4 tiles of 64 rows,
//   tj = (blk&15) + 16*j.  LDS: f16 double-buffer 2 x [64][512] = 128 KiB,
//   R1's xor-chunk swizzle + K-loop verbatim.
//   B: 16kb x 2nt half8 = 128 VGPR persistent, loaded FIRST (oldest vmem so no
//   later wait queues behind streaming loads), residency FORCED by empty
//   "+v" asm pins each iteration (defeats restrict-remat, R4's failure).
//   A stream: reg-staged in 2 chunks of 8 float4 (T14 issue-early/write-late):
//   chunk0 issued at iter start (flies under K-loop), written after K-loop;
//   chunk1 issued after B_b (flies under score+context), written after context.
//   sched_barrier(0) after each issue blocks sinking (R3's failure).
//   2 raw barriers/tile (buffer-ready, sred-ready) + lgkmcnt(0) only — in-flight
//   globals never drained by a barrier.  Score computed redundantly by all
//   waves from sred; broadcast via __shfl (no s_lds barrier).
__global__ __launch_bounds__(512, 2) void gemm_fused_kernel(
        const float* __restrict__ value,
        const float* __restrict__ last_attn,
        const float* __restrict__ conv_w,
        const float* __restrict__ w_score,
        const float* __restrict__ b_score,
        const _Float16* __restrict__ Bpack,
        const float* __restrict__ qb,
        float* __restrict__ sbuf,
        float* __restrict__ ssum,
        float* __restrict__ ctx) {
    extern __shared__ _Float16 As[];    // 2 * 64 * 512 f16 = 131072 B
    __shared__ float sred[64][9];
    __shared__ float la_s[66];          // halo [t0-1 .. t0+64] of current tile

    int tid = threadIdx.x;
    int blk = blockIdx.x;
    int b = blk >> 4;
    int ts = blk & 15;

    int lane = tid & 63, ng = tid >> 6;
    int quad = lane >> 4, lm = lane & 15;
    int srow = tid >> 3, scc = tid & 7;

    // ---- persistent B fragments: issued before ALL other vmem ----
    const _Float16* bp0 = Bpack + (size_t)(ng * 2) * 512 + lane * 8;
    half8 breg[16][2];
    #pragma unroll
    for (int kb = 0; kb < 16; ++kb) {
        breg[kb][0] = *(const half8*)(bp0 + (size_t)kb * 16384);
        breg[kb][1] = *(const half8*)(bp0 + (size_t)kb * 16384 + 512);
    }

    // ---- epilogue scalars (constant across tiles) ----
    float qvv[2], c0v[2], c1v[2], c2v[2], wvv[2];
    #pragma unroll
    for (int nt = 0; nt < 2; ++nt) {
        int o = ng * 32 + nt * 16 + lm;
        qvv[nt] = qb[b * HH + o];
        c0v[nt] = conv_w[o * 3 + 0];
        c1v[nt] = conv_w[o * 3 + 1];
        c2v[nt] = conv_w[o * 3 + 2];
        wvv[nt] = w_score[o];
    }
    float bsc = b_score[0];

    // ---- prologue: stage tile 0 into buf 0, la_s for tile 0 ----
    {
        const float4* pA = (const float4*)(value + ((size_t)b * TT + (size_t)ts * 64 + srow) * HH);
        float4 g[16];
        #pragma unroll
        for (int u = 0; u < 8; ++u) {
            int c = scc + u * 8;
            g[2 * u] = pA[2 * c]; g[2 * u + 1] = pA[2 * c + 1];
        }
        #pragma unroll
        for (int u = 0; u < 8; ++u) {
            int c = scc + u * 8;
            int cph = c ^ (srow & 7);
            float4 v0 = g[2 * u], v1 = g[2 * u + 1];
            half8 h = { (_Float16)v0.x, (_Float16)v0.y, (_Float16)v0.z, (_Float16)v0.w,
                        (_Float16)v1.x, (_Float16)v1.y, (_Float16)v1.z, (_Float16)v1.w };
            *(half8*)(As + srow * 512 + cph * 8) = h;
        }
        if (tid < 66) {
            int tg = ts * 64 - 1 + tid;
            la_s[tid] = (tg >= 0 && tg < TT) ? last_attn[(size_t)b * TT + tg] : 0.f;
        }
    }

    float ctx_acc = 0.f, tot_acc = 0.f;

    for (int j = 0; j < 4; ++j) {
        int cur = j & 1;
        int t0 = (ts + 16 * j) * 64;
        _Float16* Ab = As + cur * 32768;
        _Float16* An = As + (cur ^ 1) * 32768;

        ASM_LGKM0();
        __builtin_amdgcn_s_barrier();       // B_a: buf[cur] + la_s(tile j) ready

        // force B residency (empty asm "modifies" breg -> no remat/re-load)
        PIN8(breg[0][0],breg[0][1],breg[1][0],breg[1][1],breg[2][0],breg[2][1],breg[3][0],breg[3][1]);
        PIN8(breg[4][0],breg[4][1],breg[5][0],breg[5][1],breg[6][0],breg[6][1],breg[7][0],breg[7][1]);
        PIN8(breg[8][0],breg[8][1],breg[9][0],breg[9][1],breg[10][0],breg[10][1],breg[11][0],breg[11][1]);
        PIN8(breg[12][0],breg[12][1],breg[13][0],breg[13][1],breg[14][0],breg[14][1],breg[15][0],breg[15][1]);

        // issue G chunk0 for tile j+1 (flies under the K-loop)
        const float4* pAn = (const float4*)(value + ((size_t)b * TT + (size_t)(ts + 16 * (j + 1)) * 64 + srow) * HH);
        float4 g0[8];
        if (j < 3) {
            #pragma unroll
            for (int u = 0; u < 4; ++u) {
                int c = scc + u * 8;
                g0[2 * u] = pAn[2 * c]; g0[2 * u + 1] = pAn[2 * c + 1];
            }
            __builtin_amdgcn_sched_barrier(0);   // don't sink the loads
        }

        // ---- K-loop: A frags from LDS (f16), B from pinned regs ----
        f32x4 acc[4][2];
        #pragma unroll
        for (int mt = 0; mt < 4; ++mt) {
            f32x4 z = {0.f, 0.f, 0.f, 0.f};
            acc[mt][0] = z; acc[mt][1] = z;
        }
        #pragma unroll
        for (int kb = 0; kb < 16; ++kb) {
            #pragma unroll
            for (int mt = 0; mt < 4; ++mt) {
                int tr = mt * 16 + lm;
                int cph = ((kb << 2) + quad) ^ (tr & 7);
                half8 a = *(const half8*)(Ab + tr * 512 + cph * 8);
                acc[mt][0] = __builtin_amdgcn_mfma_f32_16x16x32_f16(a, breg[kb][0], acc[mt][0], 0, 0, 0);
                acc[mt][1] = __builtin_amdgcn_mfma_f32_16x16x32_f16(a, breg[kb][1], acc[mt][1], 0, 0, 0);
            }
        }
        __builtin_amdgcn_sched_barrier(0);       // keep cvt/wait out of the MFMA block

        // write chunk0 -> buf[cur^1] (free since last iter's context finished)
        if (j < 3) {
            #pragma unroll
            for (int u = 0; u < 4; ++u) {
                int c = scc + u * 8;
                int cph = c ^ (srow & 7);
                float4 v0 = g0[2 * u], v1 = g0[2 * u + 1];
                half8 h = { (_Float16)v0.x, (_Float16)v0.y, (_Float16)v0.z, (_Float16)v0.w,
                            (_Float16)v1.x, (_Float16)v1.y, (_Float16)v1.z, (_Float16)v1.w };
                *(half8*)(An + srow * 512 + cph * 8) = h;
            }
        }

        // ---- epilogue: conv + tanh + w_score dot -> sred ----
        #pragma unroll
        for (int mt = 0; mt < 4; ++mt) {
            float rsj[4];
            #pragma unroll
            for (int jx = 0; jx < 4; ++jx) {
                int tl = mt * 16 + quad * 4 + jx;
                float lam = la_s[tl];
                float la0 = la_s[tl + 1];
                float lap = la_s[tl + 2];
                float r = 0.f;
                #pragma unroll
                for (int nt = 0; nt < 2; ++nt) {
                    float act = acc[mt][nt][jx] + qvv[nt]
                              + c0v[nt] * lam + c1v[nt] * la0 + c2v[nt] * lap;
                    act = fminf(15.f, fmaxf(-15.f, act));
                    float e2 = __expf(2.f * act);
                    r += (1.f - 2.f * fast_rcp(e2 + 1.f)) * wvv[nt];
                }
                #pragma unroll
                for (int off = 1; off < 16; off <<= 1) r += __shfl_xor(r, off, 64);
                rsj[jx] = r;
            }
            if (lm == 0)
                #pragma unroll
                for (int jx = 0; jx < 4; ++jx)
                    sred[mt * 16 + quad * 4 + jx][ng] = rsj[jx];
        }
        ASM_LGKM0();
        __builtin_amdgcn_s_barrier();       // B_b: sred visible

        // issue G chunk1 + la_s(tile j+1) (fly under score + context)
        float4 g1[8];
        if (j < 3) {
            #pragma unroll
            for (int u = 0; u < 4; ++u) {
                int c = scc + (u + 4) * 8;
                g1[2 * u] = pAn[2 * c]; g1[2 * u + 1] = pAn[2 * c + 1];
            }
            if (tid < 66) {
                int tg = (ts + 16 * (j + 1)) * 64 - 1 + tid;
                la_s[tid] = (tg >= 0 && tg < TT) ? last_attn[(size_t)b * TT + tg] : 0.f;
            }
            __builtin_amdgcn_sched_barrier(0);
        }

        // ---- score: all waves redundant (row = lane), same sum order as before ----
        float sc = bsc;
        #pragma unroll
        for (int k = 0; k < 8; ++k) sc += sred[lane][k];
        float s = fast_rcp(1.f + __expf(-sc));
        if (tid < 64) {
            sbuf[(size_t)b * TT + t0 + tid] = s;
            tot_acc += s;
        }

        // ---- context partial from resident f16 tile: one column per thread ----
        {
            int cl = tid >> 3, jj = tid & 7;
            float a = 0.f;
            #pragma unroll 8
            for (int t2 = 0; t2 < 64; ++t2) {
                float sv = __shfl(s, t2, 64);
                int cph = cl ^ (t2 & 7);
                a += sv * (float)Ab[t2 * 512 + cph * 8 + jj];
            }
            ctx_acc += a;
        }
        __builtin_amdgcn_sched_barrier(0);

        // write chunk1 -> buf[cur^1]
        if (j < 3) {
            #pragma unroll
            for (int u = 0; u < 4; ++u) {
                int c = scc + (u + 4) * 8;
                int cph = c ^ (srow & 7);
                float4 v0 = g1[2 * u], v1 = g1[2 * u + 1];
                half8 h = { (_Float16)v0.x, (_Float16)v0.y, (_Float16)v0.z, (_Float16)v0.w,
                            (_Float16)v1.x, (_Float16)v1.y, (_Float16)v1.z, (_Float16)v1.w };
                *(half8*)(An + srow * 512 + cph * 8) = h;
            }
        }
    }

    atomicAdd(&ctx[b * HH + tid], ctx_acc);
    if (tid < 64) {
        float tot = tot_acc;
        #pragma unroll
        for (int off = 1; off < 64; off <<= 1) tot += __shfl_xor(tot, off, 64);
        if (tid == 0) atomicAdd(&ssum[b], tot);
    }
}

// ---------------- finalize: out = [ctx/ssum, query] ++ attn = s/ssum -----------
__global__ void finalize_kernel(const float* __restrict__ query,
                                const float* __restrict__ ctx,
                                const float* __restrict__ sbuf,
                                const float* __restrict__ ssum,
                                float* __restrict__ out) {
    int idx = blockIdx.x * 256 + threadIdx.x;
    if (idx < BB * 2 * HH) {
        int b = idx >> 10, c = idx & 1023;
        float v;
        if (c < HH) v = ctx[b * HH + c] / ssum[b];
        else        v = query[b * HH + (c - HH)];
        out[idx] = v;
    } else {
        int j = idx - BB * 2 * HH;
        int b = j >> 12, t = j & 4095;
        out[idx] = sbuf[b * TT + t] / ssum[b];
    }
}

extern "C" void kernel_launch(void* const* d_in, const int* in_sizes, int n_in,
                              void* d_out, int out_size, void* d_ws, size_t ws_size,
                              hipStream_t stream) {
    const float* query     = (const float*)d_in[0];
    const float* value     = (const float*)d_in[1];
    const float* last_attn = (const float*)d_in[2];
    const float* conv_w    = (const float*)d_in[3];
    const float* conv_b    = (const float*)d_in[4];
    const float* Wq        = (const float*)d_in[5];
    const float* Wv        = (const float*)d_in[6];
    const float* bias      = (const float*)d_in[7];
    const float* w_score   = (const float*)d_in[8];
    const float* b_score   = (const float*)d_in[9];

    char* ws = (char*)d_ws;
    _Float16* Bpack = (_Float16*)ws;           // 524288 B
    float* qb     = (float*)(ws + 524288);     // 32768 B
    float* sbuf   = (float*)(ws + 557056);     // 262144 B
    float* ssum   = (float*)(ws + 819200);     // 64 B
    float* ctx    = (float*)(ws + 819264);     // 32768 B
    float* out    = (float*)d_out;

    static bool attr_set = false;
    if (!attr_set) {
        hipFuncSetAttribute((const void*)gemm_fused_kernel,
                            hipFuncAttributeMaxDynamicSharedMemorySize, 131072);
        attr_set = true;
    }

    prep_kernel<<<193, 256, 0, stream>>>(query, conv_b, Wq, Wv, bias, Bpack, qb, ssum, ctx);
    gemm_fused_kernel<<<256, 512, 131072, stream>>>(value, last_attn, conv_w, w_score,
                                                    b_score, Bpack, qb, sbuf, ssum, ctx);
    finalize_kernel<<<320, 256, 0, stream>>>(query, ctx, sbuf, ssum, out);
}

// Round 6
// 252.622 us; speedup vs baseline: 1.2914x; 1.2914x over previous
//
#include <hip/hip_runtime.h>
#include <hip/hip_bf16.h>
#include <cstddef>

#define BB 16
#define TT 4096
#define HH 512

typedef _Float16 half8 __attribute__((ext_vector_type(8)));
typedef float f32x4 __attribute__((ext_vector_type(4)));

__device__ __forceinline__ float fast_rcp(float x) { return __builtin_amdgcn_rcpf(x); }

// asm global load dwordx4 with literal byte offset; output reg cannot be
// rematerialized or sunk by the compiler (R3/R4 failure modes).
#define GLOAD(dst, ptr, off) \
    asm volatile("global_load_dwordx4 %0, %1, off offset:" off \
                 : "=v"(dst) : "v"(ptr) : "memory")
#define WAITVM(n) do { \
    asm volatile("s_waitcnt vmcnt(" #n ")" ::: "memory"); \
    __builtin_amdgcn_sched_barrier(0); } while (0)
#define ASM_LGKM0() do { \
    asm volatile("s_waitcnt lgkmcnt(0)" ::: "memory"); \
    __builtin_amdgcn_sched_barrier(0); } while (0)

// ---------------- prep (unchanged) ---------------------------------------------
__global__ void prep_kernel(const float* __restrict__ query,
                            const float* __restrict__ conv_b,
                            const float* __restrict__ Wq,
                            const float* __restrict__ Wv,
                            const float* __restrict__ bias,
                            _Float16* __restrict__ Bpack,
                            float* __restrict__ qb,
                            float* __restrict__ ssum,
                            float* __restrict__ ctx) {
    int blk = blockIdx.x;
    int tid = threadIdx.x;
    if (blk < 128) {
        int tn = blk >> 2, kq = blk & 3;
        int kb = kq * 4 + (tid >> 6);
        int lane = tid & 63;
        int n = tn * 16 + (lane & 15);
        int k = kb * 32 + ((lane >> 4) << 3);
        const float4* src = (const float4*)(Wv + (size_t)n * HH + k);
        float4 v0 = src[0], v1 = src[1];
        half8 h = { (_Float16)v0.x, (_Float16)v0.y, (_Float16)v0.z, (_Float16)v0.w,
                    (_Float16)v1.x, (_Float16)v1.y, (_Float16)v1.z, (_Float16)v1.w };
        *(half8*)(Bpack + ((size_t)(kb * 32 + tn) * 64 + lane) * 8) = h;
    } else if (blk < 192) {
        int q = blk - 128;
        int b = q >> 2, oq = q & 3;
        __shared__ float qrow[HH];
        for (int i = tid; i < HH; i += 256) qrow[i] = query[b * HH + i];
        __syncthreads();
        int wave = tid >> 6, lane = tid & 63;
        float4 q1 = *(const float4*)(qrow + lane * 8);
        float4 q2 = *(const float4*)(qrow + lane * 8 + 4);
        for (int i = wave; i < 128; i += 4) {
            int o = oq * 128 + i;
            const float4* w = (const float4*)(Wq + (size_t)o * HH);
            float4 a = w[lane * 2], c = w[lane * 2 + 1];
            float acc = a.x * q1.x + a.y * q1.y + a.z * q1.z + a.w * q1.w
                      + c.x * q2.x + c.y * q2.y + c.z * q2.z + c.w * q2.w;
            #pragma unroll
            for (int off = 1; off < 64; off <<= 1) acc += __shfl_xor(acc, off, 64);
            if (lane == 0) qb[b * HH + o] = acc + bias[o] + conv_b[o];
        }
    } else {
        for (int i = tid; i < BB; i += 256) ssum[i] = 0.f;
        for (int i = tid; i < BB * HH; i += 256) ctx[i] = 0.f;
    }
}

// ---------------- fused GEMM + conv + tanh + score + sigmoid + context ---------
// Persistent counted-vmcnt pipeline: grid 256 = 1 block/CU, 512 thr = 8 waves;
// b = blk>>4, 4 tiles of 64 rows (tj = (blk&15) + 16*j).  A16 LDS dbuf 128 KiB,
// R1's xor swizzle + K-loop verbatim.  ALL steady-state vmem is inline asm:
//   B ring depth 4 (asm, 32 VGPR): per kb wait vmcnt(6) -> MFMA -> issue kb+4.
//   K-loop drains to vmcnt(0) at kb=15 (A not yet issued -> clean queue).
//   Then 16 asm A-loads (tile j+1, one base + literal offsets) + next B0..3 fly
//   under epilogue/score/context (~1.5K cyc); vmcnt(8) -> cvt -> ds_write ->
//   lgkm0 -> barrier.  last_attn pre-staged to LDS la_all[4][68] (no compiler
//   vmem in the loop except the single sbuf store, youngest in queue - counts
//   verified safe).  2 raw barriers/tile.  Numerics identical to R1/R5.
__global__ __launch_bounds__(512, 2) void gemm_fused_kernel(
        const float* __restrict__ value,
        const float* __restrict__ last_attn,
        const float* __restrict__ conv_w,
        const float* __restrict__ w_score,
        const float* __restrict__ b_score,
        const _Float16* __restrict__ Bpack,
        const float* __restrict__ qb,
        float* __restrict__ sbuf,
        float* __restrict__ ssum,
        float* __restrict__ ctx) {
    extern __shared__ _Float16 As[];    // 2 * 64 * 512 f16 = 131072 B
    __shared__ float sred[64][9];
    __shared__ float la_all[4][68];     // last_attn halo per tile

    int tid = threadIdx.x;
    int blk = blockIdx.x;
    int b = blk >> 4;
    int ts = blk & 15;

    int lane = tid & 63, ng = tid >> 6;
    int quad = lane >> 4, lm = lane & 15;
    int srow = tid >> 3, scc = tid & 7;

    // ---- compiler loads (all BEFORE any asm vmem) ----
    float qvv[2], c0v[2], c1v[2], c2v[2], wvv[2];
    #pragma unroll
    for (int nt = 0; nt < 2; ++nt) {
        int o = ng * 32 + nt * 16 + lm;
        qvv[nt] = qb[b * HH + o];
        c0v[nt] = conv_w[o * 3 + 0];
        c1v[nt] = conv_w[o * 3 + 1];
        c2v[nt] = conv_w[o * 3 + 2];
        wvv[nt] = w_score[o];
    }
    float bsc = b_score[0];
    if (tid < 66) {
        #pragma unroll
        for (int jt = 0; jt < 4; ++jt) {
            int tg = (ts + 16 * jt) * 64 - 1 + tid;
            la_all[jt][tid] = (tg >= 0 && tg < TT) ? last_attn[(size_t)b * TT + tg] : 0.f;
        }
    }

    const char* bp0c = (const char*)Bpack + ng * 2048 + lane * 16;
    half8 breg[4][2];
    f32x4 ga[16];

    auto issueA = [&](int tj) {
        const char* ap = (const char*)(value + ((size_t)b * TT + (size_t)tj * 64 + srow) * HH) + scc * 32;
        GLOAD(ga[0],  ap, "0");    GLOAD(ga[1],  ap, "16");
        GLOAD(ga[2],  ap, "256");  GLOAD(ga[3],  ap, "272");
        GLOAD(ga[4],  ap, "512");  GLOAD(ga[5],  ap, "528");
        GLOAD(ga[6],  ap, "768");  GLOAD(ga[7],  ap, "784");
        GLOAD(ga[8],  ap, "1024"); GLOAD(ga[9],  ap, "1040");
        GLOAD(ga[10], ap, "1280"); GLOAD(ga[11], ap, "1296");
        GLOAD(ga[12], ap, "1536"); GLOAD(ga[13], ap, "1552");
        GLOAD(ga[14], ap, "1792"); GLOAD(ga[15], ap, "1808");
    };
    auto issueB0123 = [&]() {
        const char* p0 = bp0c;
        const char* p1 = bp0c + 32768;
        const char* p2 = bp0c + 65536;
        const char* p3 = bp0c + 98304;
        GLOAD(breg[0][0], p0, "0"); GLOAD(breg[0][1], p0, "1024");
        GLOAD(breg[1][0], p1, "0"); GLOAD(breg[1][1], p1, "1024");
        GLOAD(breg[2][0], p2, "0"); GLOAD(breg[2][1], p2, "1024");
        GLOAD(breg[3][0], p3, "0"); GLOAD(breg[3][1], p3, "1024");
    };
    auto cvtW = [&](_Float16* Adst) {
        #pragma unroll
        for (int u = 0; u < 8; ++u) {
            int c = scc + u * 8, cph = c ^ (srow & 7);
            f32x4 v0 = ga[u * 2], v1 = ga[u * 2 + 1];
            half8 h = { (_Float16)v0.x, (_Float16)v0.y, (_Float16)v0.z, (_Float16)v0.w,
                        (_Float16)v1.x, (_Float16)v1.y, (_Float16)v1.z, (_Float16)v1.w };
            *(half8*)(Adst + srow * 512 + cph * 8) = h;
        }
    };

    // ---- prologue: tile 0 stage + B ring fill ----
    issueA(ts);
    issueB0123();
    WAITVM(8);                          // A landed, B0..3 flying
    cvtW(As);
    ASM_LGKM0();
    __builtin_amdgcn_s_barrier();

    float ctx_acc = 0.f, tot_acc = 0.f;
    int cur = 0;

    for (int j = 0; j < 4; ++j) {
        _Float16* Acur = As + cur * 32768;
        _Float16* Anxt = As + (cur ^ 1) * 32768;
        int t0 = (ts + 16 * j) * 64;

        // ---- K-loop: asm B ring depth 4, counted vmcnt ----
        f32x4 acc[4][2];
        #pragma unroll
        for (int mt = 0; mt < 4; ++mt) {
            f32x4 z = {0.f, 0.f, 0.f, 0.f};
            acc[mt][0] = z; acc[mt][1] = z;
        }
        const char* bpp = bp0c + 4 * 32768;
        #pragma unroll
        for (int kb = 0; kb < 16; ++kb) {
            if (kb <= 12)      WAITVM(6);
            else if (kb == 13) WAITVM(4);
            else if (kb == 14) WAITVM(2);
            else               WAITVM(0);
            #pragma unroll
            for (int mt = 0; mt < 4; ++mt) {
                int tr = mt * 16 + lm;
                int cph = ((kb << 2) + quad) ^ (tr & 7);
                half8 a = *(const half8*)(Acur + tr * 512 + cph * 8);
                acc[mt][0] = __builtin_amdgcn_mfma_f32_16x16x32_f16(a, breg[kb & 3][0], acc[mt][0], 0, 0, 0);
                acc[mt][1] = __builtin_amdgcn_mfma_f32_16x16x32_f16(a, breg[kb & 3][1], acc[mt][1], 0, 0, 0);
            }
            if (kb < 12) {
                GLOAD(breg[kb & 3][0], bpp, "0");
                GLOAD(breg[kb & 3][1], bpp, "1024");
                bpp += 32768;
            }
        }

        // ---- issue next tile's A + B ring (fly under epilogue/score/context) ----
        if (j < 3) {
            issueA(ts + 16 * (j + 1));
            issueB0123();
        }

        // ---- epilogue: conv + tanh + w_score dot -> sred ----
        #pragma unroll
        for (int mt = 0; mt < 4; ++mt) {
            float rsj[4];
            #pragma unroll
            for (int jx = 0; jx < 4; ++jx) {
                int tl = mt * 16 + quad * 4 + jx;
                float lam = la_all[j][tl];
                float la0 = la_all[j][tl + 1];
                float lap = la_all[j][tl + 2];
                float r = 0.f;
                #pragma unroll
                for (int nt = 0; nt < 2; ++nt) {
                    float act = acc[mt][nt][jx] + qvv[nt]
                              + c0v[nt] * lam + c1v[nt] * la0 + c2v[nt] * lap;
                    act = fminf(15.f, fmaxf(-15.f, act));
                    float e2 = __expf(2.f * act);
                    r += (1.f - 2.f * fast_rcp(e2 + 1.f)) * wvv[nt];
                }
                #pragma unroll
                for (int off = 1; off < 16; off <<= 1) r += __shfl_xor(r, off, 64);
                rsj[jx] = r;
            }
            if (lm == 0)
                #pragma unroll
                for (int jx = 0; jx < 4; ++jx)
                    sred[mt * 16 + quad * 4 + jx][ng] = rsj[jx];
        }
        ASM_LGKM0();
        __builtin_amdgcn_s_barrier();       // sred visible

        // ---- score: redundant per wave; wave 0 stores ----
        float sc = bsc;
        #pragma unroll
        for (int k = 0; k < 8; ++k) sc += sred[lane][k];
        float s = fast_rcp(1.f + __expf(-sc));
        if (tid < 64) {
            sbuf[(size_t)b * TT + t0 + tid] = s;
            tot_acc += s;
        }

        // ---- context partial: one column per thread, s via shfl ----
        {
            int cl = tid >> 3, jj = tid & 7;
            float a = 0.f;
            #pragma unroll 8
            for (int t2 = 0; t2 < 64; ++t2) {
                float sv = __shfl(s, t2, 64);
                int cph2 = cl ^ (t2 & 7);
                a += sv * (float)Acur[t2 * 512 + cph2 * 8 + jj];
            }
            ctx_acc += a;
        }

        // ---- stage write: A for tile j+1 landed under the work above ----
        if (j < 3) {
            WAITVM(8);                      // A done, next B0..3 still flying
            cvtW(Anxt);
            ASM_LGKM0();
            __builtin_amdgcn_s_barrier();   // buf[nxt] ready
            cur ^= 1;
        }
    }

    atomicAdd(&ctx[b * HH + tid], ctx_acc);
    if (tid < 64) {
        float tot = tot_acc;
        #pragma unroll
        for (int off = 1; off < 64; off <<= 1) tot += __shfl_xor(tot, off, 64);
        if (tid == 0) atomicAdd(&ssum[b], tot);
    }
}

// ---------------- finalize: out = [ctx/ssum, query] ++ attn = s/ssum -----------
__global__ void finalize_kernel(const float* __restrict__ query,
                                const float* __restrict__ ctx,
                                const float* __restrict__ sbuf,
                                const float* __restrict__ ssum,
                                float* __restrict__ out) {
    int idx = blockIdx.x * 256 + threadIdx.x;
    if (idx < BB * 2 * HH) {
        int b = idx >> 10, c = idx & 1023;
        float v;
        if (c < HH) v = ctx[b * HH + c] / ssum[b];
        else        v = query[b * HH + (c - HH)];
        out[idx] = v;
    } else {
        int j = idx - BB * 2 * HH;
        int b = j >> 12, t = j & 4095;
        out[idx] = sbuf[b * TT + t] / ssum[b];
    }
}

extern "C" void kernel_launch(void* const* d_in, const int* in_sizes, int n_in,
                              void* d_out, int out_size, void* d_ws, size_t ws_size,
                              hipStream_t stream) {
    const float* query     = (const float*)d_in[0];
    const float* value     = (const float*)d_in[1];
    const float* last_attn = (const float*)d_in[2];
    const float* conv_w    = (const float*)d_in[3];
    const float* conv_b    = (const float*)d_in[4];
    const float* Wq        = (const float*)d_in[5];
    const float* Wv        = (const float*)d_in[6];
    const float* bias      = (const float*)d_in[7];
    const float* w_score   = (const float*)d_in[8];
    const float* b_score   = (const float*)d_in[9];

    char* ws = (char*)d_ws;
    _Float16* Bpack = (_Float16*)ws;           // 524288 B
    float* qb     = (float*)(ws + 524288);     // 32768 B
    float* sbuf   = (float*)(ws + 557056);     // 262144 B
    float* ssum   = (float*)(ws + 819200);     // 64 B
    float* ctx    = (float*)(ws + 819264);     // 32768 B
    float* out    = (float*)d_out;

    static bool attr_set = false;
    if (!attr_set) {
        hipFuncSetAttribute((const void*)gemm_fused_kernel,
                            hipFuncAttributeMaxDynamicSharedMemorySize, 131072);
        attr_set = true;
    }

    prep_kernel<<<193, 256, 0, stream>>>(query, conv_b, Wq, Wv, bias, Bpack, qb, ssum, ctx);
    gemm_fused_kernel<<<256, 512, 131072, stream>>>(value, last_attn, conv_w, w_score,
                                                    b_score, Bpack, qb, sbuf, ssum, ctx);
    finalize_kernel<<<320, 256, 0, stream>>>(query, ctx, sbuf, ssum, out);
}